// Round 5
// baseline (144.116 us; speedup 1.0000x reference)
//
#include <hip/hip_runtime.h>

typedef __attribute__((ext_vector_type(8))) short short8;
typedef __attribute__((ext_vector_type(4))) float f32x4;

#define GLDS16(gp, lp)                                                                     \
  __builtin_amdgcn_global_load_lds(                                                        \
      (const __attribute__((address_space(1))) unsigned int*)(gp),                         \
      (__attribute__((address_space(3))) unsigned int*)(lp), 16, 0, 0)

__device__ __forceinline__ unsigned short f2bf(float f) {
  unsigned u = __float_as_uint(f);
  u += 0x7FFFu + ((u >> 16) & 1u);
  return (unsigned short)(u >> 16);
}
__device__ __forceinline__ float bf2f(unsigned short h) {
  return __uint_as_float(((unsigned)h) << 16);
}
__device__ __forceinline__ unsigned cvt_pk_bf16(float a, float b) {
  unsigned r;
  asm("v_cvt_pk_bf16_f32 %0, %1, %2" : "=v"(r) : "v"(a), "v"(b));
  return r;  // lo16 = bf16(a), hi16 = bf16(b)
}

#define QSCALE 0.1803368801111244f  /* 0.125 * log2(e): QK logits land in exp2 domain */

// ---------------------------------------------------------------------------
// prep_x: x -> bf16 (vectorized), jmbf[b][j] = masked ? -100 : 1e30 (bf16)
// ---------------------------------------------------------------------------
__global__ __launch_bounds__(256) void prep_x(
    const float* __restrict__ x, const int* __restrict__ mnp, const int* __restrict__ mbert,
    unsigned short* __restrict__ xb, unsigned short* __restrict__ jmbf) {
  int tid = blockIdx.x * 256 + threadIdx.x;
  if (tid < 524288) {
    float4 v = *(const float4*)(x + tid * 4);
    ushort4 o;
    o.x = f2bf(v.x); o.y = f2bf(v.y); o.z = f2bf(v.z); o.w = f2bf(v.w);
    *(ushort4*)(xb + tid * 4) = o;
  } else {
    int o = tid - 524288;
    if (o < 4096) jmbf[o] = (mnp[o] == 0 || mbert[o] == 1) ? f2bf(-100.0f) : f2bf(1e30f);
  }
}

// ---------------------------------------------------------------------------
// transpose_w: LDS-tiled 64x64 transpose, coalesced read AND write.
// ---------------------------------------------------------------------------
__global__ __launch_bounds__(256) void transpose_w(
    const float* __restrict__ wqkv, const float* __restrict__ wout,
    unsigned short* __restrict__ wqkvT, unsigned short* __restrict__ whiT,
    unsigned short* __restrict__ wloT) {
  __shared__ float tile[64][65];
  int bid = blockIdx.x;
  const float* src;
  int N, k0, n0, which;
  if (bid < 192) { which = 0; src = wqkv; N = 1536; k0 = (bid / 24) * 64; n0 = (bid % 24) * 64; }
  else { bid -= 192; which = 1; src = wout; N = 512; k0 = (bid / 8) * 64; n0 = (bid % 8) * 64; }
  int tx = threadIdx.x & 63, ty = threadIdx.x >> 6;
#pragma unroll
  for (int i = 0; i < 16; ++i) {
    int row = ty + i * 4;
    tile[row][tx] = src[(k0 + row) * N + n0 + tx];
  }
  __syncthreads();
#pragma unroll
  for (int i = 0; i < 16; ++i) {
    int row = ty + i * 4;
    float w = tile[tx][row];
    if (which == 0) {
      wqkvT[(n0 + row) * 512 + k0 + tx] = f2bf(w);
    } else {
      unsigned short hi = f2bf(w);
      whiT[(n0 + row) * 512 + k0 + tx] = hi;
      wloT[(n0 + row) * 512 + k0 + tx] = f2bf(w - bf2f(hi));
    }
  }
}

// ---------------------------------------------------------------------------
// qkv_gemm v2: double-buffered LDS + counted vmcnt(6) + raw barriers.
// 64x128 tile, 4 waves, BK=64. V-part epilogue transposed via LDS so vtb
// ([b,h,d,n]) gets 64B-contiguous stores instead of 2B scatter.
// ---------------------------------------------------------------------------
__global__ __launch_bounds__(256) void qkv_gemm(
    const unsigned short* __restrict__ A, const unsigned short* __restrict__ Bt,
    unsigned short* __restrict__ qb, unsigned short* __restrict__ kb,
    unsigned short* __restrict__ vtb) {
  __shared__ __attribute__((aligned(16))) unsigned short lA[2][64 * 64];   // 16 KB
  __shared__ __attribute__((aligned(16))) unsigned short lB[2][128 * 64];  // 32 KB
  const int lane = threadIdx.x & 63, wid = threadIdx.x >> 6;
  const int l15 = lane & 15, lg = lane >> 4;
  const int row0 = blockIdx.x * 64;
  const int col0 = blockIdx.y * 128;
  const int srow = lane >> 3;
  const int gslot = (lane & 7) ^ srow;
  f32x4 acc[4][2] = {};

#define QKV_STAGE(ks_, buf_)                                                               \
  {                                                                                        \
    const int k0_ = (ks_) * 64;                                                            \
    _Pragma("unroll") for (int i = 0; i < 2; ++i) {                                        \
      int c = wid * 2 + i;                                                                 \
      GLDS16(A + (row0 + c * 8 + srow) * 512 + k0_ + gslot * 8, &lA[buf_][c * 512]);       \
    }                                                                                      \
    _Pragma("unroll") for (int i = 0; i < 4; ++i) {                                        \
      int c = wid * 4 + i;                                                                 \
      GLDS16(Bt + (col0 + c * 8 + srow) * 512 + k0_ + gslot * 8, &lB[buf_][c * 512]);      \
    }                                                                                      \
  }

  QKV_STAGE(0, 0);
  int buf = 0;
  for (int ks = 0; ks < 8; ++ks) {
    if (ks < 7) {
      QKV_STAGE(ks + 1, buf ^ 1);
      asm volatile("s_waitcnt vmcnt(6)" ::: "memory");  // current tile landed, next in flight
    } else {
      asm volatile("s_waitcnt vmcnt(0)" ::: "memory");
    }
    __builtin_amdgcn_s_barrier();
    const unsigned short* La = &lA[buf][0];
    const unsigned short* Lb = &lB[buf][0];
#pragma unroll
    for (int ksub = 0; ksub < 2; ++ksub) {
      short8 af[4], bfr[2];
#pragma unroll
      for (int m = 0; m < 4; ++m) {
        int row = m * 16 + l15;
        int slot = (ksub * 4 + lg) ^ (row & 7);
        af[m] = *(const short8*)(La + row * 64 + slot * 8);
      }
#pragma unroll
      for (int n = 0; n < 2; ++n) {
        int row = wid * 32 + n * 16 + l15;
        int slot = (ksub * 4 + lg) ^ (row & 7);
        bfr[n] = *(const short8*)(Lb + row * 64 + slot * 8);
      }
#pragma unroll
      for (int m = 0; m < 4; ++m)
#pragma unroll
        for (int n = 0; n < 2; ++n)
          acc[m][n] = __builtin_amdgcn_mfma_f32_16x16x32_bf16(af[m], bfr[n], acc[m][n], 0, 0, 0);
    }
    __builtin_amdgcn_s_barrier();  // all waves done with buf before it is restaged
    buf ^= 1;
  }

  if (col0 >= 1024) {
    // ---- V block: transpose via LDS scratch ([128][72] shorts over lB, 18 KB)
    unsigned short* T = &lB[0][0];
#pragma unroll
    for (int m = 0; m < 4; ++m)
#pragma unroll
      for (int n = 0; n < 2; ++n) {
        int lc = wid * 32 + n * 16 + l15;
#pragma unroll
        for (int r = 0; r < 4; ++r)
          T[lc * 72 + m * 16 + lg * 4 + r] = f2bf(acc[m][n][r]);
      }
    __syncthreads();
    int c = threadIdx.x >> 1, half = threadIdx.x & 1;
    int gcol = col0 + c;
    int hh = (gcol >> 6) & 7, d = gcol & 63;
    int b = row0 >> 11, np0 = row0 & 2047;
    unsigned short* dst = vtb + ((size_t)((b * 8 + hh) * 64 + d)) * 2048 + np0 + half * 32;
    const unsigned short* srcT = T + c * 72 + half * 32;
#pragma unroll
    for (int i = 0; i < 4; ++i)
      *(short8*)(dst + i * 8) = *(const short8*)(srcT + i * 8);
  } else {
#pragma unroll
    for (int m = 0; m < 4; ++m) {
#pragma unroll
      for (int n = 0; n < 2; ++n) {
        int col = col0 + wid * 32 + n * 16 + l15;
        int which = col >> 9, hh = (col >> 6) & 7, d = col & 63;
#pragma unroll
        for (int r = 0; r < 4; ++r) {
          int grow = row0 + m * 16 + lg * 4 + r;
          int b = grow >> 11, np = grow & 2047;
          float v = acc[m][n][r];
          if (which == 0)
            qb[((b * 8 + hh) * 2048 + np) * 64 + d] = f2bf(v * QSCALE);  // exp2-domain scale
          else
            kb[((b * 8 + hh) * 2048 + np) * 64 + d] = f2bf(v);
        }
      }
    }
  }
}

// ---------------------------------------------------------------------------
// attn_kernel v4: 4-buffer 2-deep prefetch, ONE barrier per j-tile.
// Grid (16 bh, 32 q-blocks of 64), 4 waves; wave owns 16 q-rows; 32 j-tiles.
// Race safety: stage at iter jt targets buf (jt+2)%4; concurrent readers only
// touch bufs (jt-1)%4 / jt%4 (waves skew <1 iter around the single barrier).
// vmcnt(8) = 2 tiles in flight; tails 4/0. Fixed-max exp2 softmax.
// ---------------------------------------------------------------------------
__global__ __launch_bounds__(256) void attn_kernel(
    const unsigned short* __restrict__ qg, const unsigned short* __restrict__ kg,
    const unsigned short* __restrict__ vtg, const int* __restrict__ mnp,
    const unsigned short* __restrict__ jmbf,
    unsigned short* __restrict__ ahi, unsigned short* __restrict__ alo) {
  __shared__ __attribute__((aligned(16))) unsigned short Kbuf[4][64 * 64];  // 32 KB
  __shared__ __attribute__((aligned(16))) unsigned short Vbuf[4][64 * 64];  // 32 KB
  __shared__ __attribute__((aligned(16))) unsigned short jmlds[2048];       // 4 KB
  __shared__ __attribute__((aligned(16))) unsigned short Plds[4][16 * 72];  // 9 KB
  const int lane = threadIdx.x & 63, wid = threadIdx.x >> 6;
  const int l15 = lane & 15, lg = lane >> 4;
  const int srow = lane >> 3, gslot = (lane & 7) ^ srow;
  const int bh = blockIdx.x, b = bh >> 3, h = bh & 7;
  const int q0 = blockIdx.y * 64 + wid * 16;
  const unsigned short* Q = qg + bh * (2048 * 64);
  const unsigned short* K = kg + bh * (2048 * 64);
  const unsigned short* VT = vtg + bh * (64 * 2048);

#define ATTN_STAGE(jt_, buf_)                                                              \
  {                                                                                        \
    const int jb_ = (jt_) * 64;                                                            \
    _Pragma("unroll") for (int i = 0; i < 2; ++i)                                          \
        GLDS16(K + (jb_ + wid * 16 + i * 8 + srow) * 64 + gslot * 8,                       \
               &Kbuf[buf_][(wid * 16 + i * 8) * 64]);                                      \
    _Pragma("unroll") for (int i = 0; i < 2; ++i)                                          \
        GLDS16(VT + (wid * 16 + i * 8 + srow) * 2048 + jb_ + gslot * 8,                    \
               &Vbuf[buf_][(wid * 16 + i * 8) * 64]);                                      \
  }

  GLDS16(jmbf + b * 2048 + wid * 512 + lane * 8, jmlds + wid * 512);
  ATTN_STAGE(0, 0);
  ATTN_STAGE(1, 1);

  short8 qf[2];
#pragma unroll
  for (int s = 0; s < 2; ++s)
    qf[s] = *(const short8*)(Q + (q0 + l15) * 64 + s * 32 + lg * 8);
  const float rowflt = (mnp[b * 2048 + q0 + l15] == 0) ? -100.0f : 1e30f;

  f32x4 accO[4] = {};
  float psum = 0.0f;
  unsigned short* Pl = &Plds[wid][0];

  for (int jt = 0; jt < 32; ++jt) {
    if (jt < 30) {
      ATTN_STAGE(jt + 2, (jt + 2) & 3);
      asm volatile("s_waitcnt vmcnt(8)" ::: "memory");  // tile jt landed; jt+1, jt+2 in flight
    } else if (jt == 30) {
      asm volatile("s_waitcnt vmcnt(4)" ::: "memory");
    } else {
      asm volatile("s_waitcnt vmcnt(0)" ::: "memory");
    }
    __builtin_amdgcn_s_barrier();

    const unsigned short* Kc = &Kbuf[jt & 3][0];
    const unsigned short* Vc = &Vbuf[jt & 3][0];
    const int j0 = jt * 64;
    const int sw = (l15 & 7) * 8;
    short8 kf[4][2], vf[4][2];
#pragma unroll
    for (int t = 0; t < 4; ++t) {
      const int row = t * 16 + l15;
#pragma unroll
      for (int s = 0; s < 2; ++s)
        kf[t][s] = *(const short8*)(&Kc[row * 64 + ((s * 32 + lg * 8) ^ sw)]);
    }
#pragma unroll
    for (int dt = 0; dt < 4; ++dt) {
      const int row = dt * 16 + l15;
#pragma unroll
      for (int c = 0; c < 2; ++c)
        vf[dt][c] = *(const short8*)(&Vc[row * 64 + ((c * 32 + lg * 8) ^ sw)]);
    }

    f32x4 sacc[4] = {};
#pragma unroll
    for (int t = 0; t < 4; ++t)
#pragma unroll
      for (int s = 0; s < 2; ++s)
        sacc[t] = __builtin_amdgcn_mfma_f32_16x16x32_bf16(kf[t][s], qf[s], sacc[t], 0, 0, 0);

#pragma unroll
    for (int t = 0; t < 4; ++t) {
      ushort4 jmv = *(const ushort4*)(&jmlds[j0 + t * 16 + lg * 4]);
      float jmf[4] = {bf2f(jmv.x), bf2f(jmv.y), bf2f(jmv.z), bf2f(jmv.w)};
      float e[4];
#pragma unroll
      for (int r = 0; r < 4; ++r) {
        float sv = fminf(fminf(sacc[t][r], jmf[r]), rowflt);  // v_min3
        e[r] = exp2f(sv);
        psum += e[r];
      }
      *(unsigned*)(Pl + l15 * 72 + t * 16 + lg * 4 + 0) = cvt_pk_bf16(e[0], e[1]);
      *(unsigned*)(Pl + l15 * 72 + t * 16 + lg * 4 + 2) = cvt_pk_bf16(e[2], e[3]);
    }
    short8 pa[2];
#pragma unroll
    for (int c = 0; c < 2; ++c)
      pa[c] = *(const short8*)(Pl + l15 * 72 + c * 32 + lg * 8);
#pragma unroll
    for (int dt = 0; dt < 4; ++dt)
#pragma unroll
      for (int c = 0; c < 2; ++c)
        accO[dt] = __builtin_amdgcn_mfma_f32_16x16x32_bf16(pa[c], vf[dt][c], accO[dt], 0, 0, 0);
  }

  // ---- epilogue: row-sum reduce, normalize, hi/lo bf16 split, direct store
  psum += __shfl_xor(psum, 16);
  psum += __shfl_xor(psum, 32);
  float lsum[4];
#pragma unroll
  for (int r = 0; r < 4; ++r) lsum[r] = 1.0f / __shfl(psum, lg * 4 + r);
#pragma unroll
  for (int dt = 0; dt < 4; ++dt) {
#pragma unroll
    for (int r = 0; r < 4; ++r) {
      float val = accO[dt][r] * lsum[r];
      int row = q0 + lg * 4 + r;
      int col = h * 64 + dt * 16 + l15;
      unsigned short hi = f2bf(val);
      ahi[(b * 2048 + row) * 512 + col] = hi;
      alo[(b * 2048 + row) * 512 + col] = f2bf(val - bf2f(hi));
    }
  }
}

// ---------------------------------------------------------------------------
// outproj_gemm v2: split-bf16 GEMM, virtual K=1536, double-buffered + vmcnt(5).
// 32x128 tile, 4 waves (each 32x32), grid (128,4).
// ---------------------------------------------------------------------------
__global__ __launch_bounds__(256) void outproj_gemm(
    const unsigned short* __restrict__ Ahi, const unsigned short* __restrict__ Alo,
    const unsigned short* __restrict__ WhiT, const unsigned short* __restrict__ WloT,
    const float* __restrict__ bias, float* __restrict__ out) {
  __shared__ __attribute__((aligned(16))) unsigned short lA[2][32 * 64];   // 8 KB
  __shared__ __attribute__((aligned(16))) unsigned short lB[2][128 * 64];  // 32 KB
  const int lane = threadIdx.x & 63, wid = threadIdx.x >> 6;
  const int l15 = lane & 15, lg = lane >> 4;
  const int row0 = blockIdx.x * 32;
  const int col0 = blockIdx.y * 128;
  const int srow = lane >> 3;
  const int gslot = (lane & 7) ^ srow;
  f32x4 acc[2][2] = {};

#define OP_STAGE(ks_, buf_)                                                                \
  {                                                                                        \
    const int seg_ = (ks_) >> 3;                                                           \
    const int k0_ = ((ks_) & 7) * 64;                                                      \
    const unsigned short* Asrc_ = (seg_ == 1) ? Alo : Ahi;                                 \
    const unsigned short* Bsrc_ = (seg_ == 2) ? WloT : WhiT;                               \
    GLDS16(Asrc_ + (row0 + wid * 8 + srow) * 512 + k0_ + gslot * 8, &lA[buf_][wid * 512]); \
    _Pragma("unroll") for (int i = 0; i < 4; ++i) {                                        \
      int c = wid * 4 + i;                                                                 \
      GLDS16(Bsrc_ + (col0 + c * 8 + srow) * 512 + k0_ + gslot * 8, &lB[buf_][c * 512]);   \
    }                                                                                      \
  }

  OP_STAGE(0, 0);
  int buf = 0;
  for (int ks = 0; ks < 24; ++ks) {
    if (ks < 23) {
      OP_STAGE(ks + 1, buf ^ 1);
      asm volatile("s_waitcnt vmcnt(5)" ::: "memory");
    } else {
      asm volatile("s_waitcnt vmcnt(0)" ::: "memory");
    }
    __builtin_amdgcn_s_barrier();
    const unsigned short* La = &lA[buf][0];
    const unsigned short* Lb = &lB[buf][0];
#pragma unroll
    for (int ksub = 0; ksub < 2; ++ksub) {
      short8 af[2], bfr[2];
#pragma unroll
      for (int m = 0; m < 2; ++m) {
        int row = m * 16 + l15;
        int slot = (ksub * 4 + lg) ^ (row & 7);
        af[m] = *(const short8*)(La + row * 64 + slot * 8);
      }
#pragma unroll
      for (int n = 0; n < 2; ++n) {
        int row = wid * 32 + n * 16 + l15;
        int slot = (ksub * 4 + lg) ^ (row & 7);
        bfr[n] = *(const short8*)(Lb + row * 64 + slot * 8);
      }
#pragma unroll
      for (int m = 0; m < 2; ++m)
#pragma unroll
        for (int n = 0; n < 2; ++n)
          acc[m][n] = __builtin_amdgcn_mfma_f32_16x16x32_bf16(af[m], bfr[n], acc[m][n], 0, 0, 0);
    }
    __builtin_amdgcn_s_barrier();
    buf ^= 1;
  }
#pragma unroll
  for (int m = 0; m < 2; ++m) {
#pragma unroll
    for (int n = 0; n < 2; ++n) {
      int col = col0 + wid * 32 + n * 16 + l15;
      float bb = bias[col];
#pragma unroll
      for (int r = 0; r < 4; ++r) {
        int grow = row0 + m * 16 + lg * 4 + r;
        out[grow * 512 + col] = acc[m][n][r] + bb;
      }
    }
  }
}

// ---------------------------------------------------------------------------
extern "C" void kernel_launch(void* const* d_in, const int* in_sizes, int n_in,
                              void* d_out, int out_size, void* d_ws, size_t ws_size,
                              hipStream_t stream) {
  (void)in_sizes; (void)n_in; (void)out_size; (void)ws_size;
  const float* x = (const float*)d_in[0];
  const int* mnp = (const int*)d_in[1];
  const int* mbert = (const int*)d_in[2];
  const float* wqkv = (const float*)d_in[3];
  const float* wout = (const float*)d_in[4];
  const float* bout = (const float*)d_in[5];
  float* out = (float*)d_out;

  char* ws = (char*)d_ws;
  size_t off = 0;
  auto alloc = [&](size_t bytes) {
    void* p = ws + off;
    off += (bytes + 255) & ~(size_t)255;
    return p;
  };
  unsigned short* xb    = (unsigned short*)alloc(2097152 * 2);   // x bf16 [4096][512]
  unsigned short* wqkvT = (unsigned short*)alloc(786432 * 2);    // [1536][512]
  unsigned short* qb    = (unsigned short*)alloc(2097152 * 2);   // [b,h,n,d] (xQSCALE)
  unsigned short* kb    = (unsigned short*)alloc(2097152 * 2);   // [b,h,n,d]
  unsigned short* vtb   = (unsigned short*)alloc(2097152 * 2);   // [b,h,d,n]
  unsigned short* ahi   = (unsigned short*)alloc(2097152 * 2);   // attn out hi
  unsigned short* alo   = (unsigned short*)alloc(2097152 * 2);   // attn out lo
  unsigned short* whiT  = (unsigned short*)alloc(262144 * 2);    // [512][512] n-major
  unsigned short* wloT  = (unsigned short*)alloc(262144 * 2);
  unsigned short* jmbf  = (unsigned short*)alloc(4096 * 2);

  prep_x<<<2064, 256, 0, stream>>>(x, mnp, mbert, xb, jmbf);
  transpose_w<<<256, 256, 0, stream>>>(wqkv, wout, wqkvT, whiT, wloT);
  qkv_gemm<<<dim3(64, 12), 256, 0, stream>>>(xb, wqkvT, qb, kb, vtb);
  attn_kernel<<<dim3(16, 32), 256, 0, stream>>>(qb, kb, vtb, mnp, jmbf, ahi, alo);
  outproj_gemm<<<dim3(128, 4), 256, 0, stream>>>(ahi, alo, whiT, wloT, bout, out);
}

// Round 6
// 133.531 us; speedup vs baseline: 1.0793x; 1.0793x over previous
//
#include <hip/hip_runtime.h>

typedef __attribute__((ext_vector_type(8))) short short8;
typedef __attribute__((ext_vector_type(4))) float f32x4;

#define GLDS16(gp, lp)                                                                     \
  __builtin_amdgcn_global_load_lds(                                                        \
      (const __attribute__((address_space(1))) unsigned int*)(gp),                         \
      (__attribute__((address_space(3))) unsigned int*)(lp), 16, 0, 0)

__device__ __forceinline__ unsigned short f2bf(float f) {
  unsigned u = __float_as_uint(f);
  u += 0x7FFFu + ((u >> 16) & 1u);
  return (unsigned short)(u >> 16);
}
__device__ __forceinline__ float bf2f(unsigned short h) {
  return __uint_as_float(((unsigned)h) << 16);
}
__device__ __forceinline__ unsigned cvt_pk_bf16(float a, float b) {
  unsigned r;
  asm("v_cvt_pk_bf16_f32 %0, %1, %2" : "=v"(r) : "v"(a), "v"(b));
  return r;  // lo16 = bf16(a), hi16 = bf16(b)
}

#define QSCALE 0.1803368801111244f  /* 0.125 * log2(e): QK logits land in exp2 domain */

// ---------------------------------------------------------------------------
// prep_x: x -> bf16 (vectorized), jmflt[b][j] = masked ? -100 : 1e30 (f32)
// ---------------------------------------------------------------------------
__global__ __launch_bounds__(256) void prep_x(
    const float* __restrict__ x, const int* __restrict__ mnp, const int* __restrict__ mbert,
    unsigned short* __restrict__ xb, float* __restrict__ jmflt) {
  int tid = blockIdx.x * 256 + threadIdx.x;
  if (tid < 524288) {
    float4 v = *(const float4*)(x + tid * 4);
    ushort4 o;
    o.x = f2bf(v.x); o.y = f2bf(v.y); o.z = f2bf(v.z); o.w = f2bf(v.w);
    *(ushort4*)(xb + tid * 4) = o;
  } else {
    int o = tid - 524288;
    if (o < 4096) jmflt[o] = (mnp[o] == 0 || mbert[o] == 1) ? -100.0f : 1e30f;
  }
}

// ---------------------------------------------------------------------------
// transpose_w: LDS-tiled 64x64 transpose, coalesced read AND write.
// blocks 0..191: wqkv [512][1536] -> wqkvT [1536][512] bf16
// blocks 192..255: wout [512][512] -> whiT [512][512] bf16 (n-major)
// ---------------------------------------------------------------------------
__global__ __launch_bounds__(256) void transpose_w(
    const float* __restrict__ wqkv, const float* __restrict__ wout,
    unsigned short* __restrict__ wqkvT, unsigned short* __restrict__ whiT) {
  __shared__ float tile[64][65];
  int bid = blockIdx.x;
  const float* src;
  int N, k0, n0, which;
  if (bid < 192) { which = 0; src = wqkv; N = 1536; k0 = (bid / 24) * 64; n0 = (bid % 24) * 64; }
  else { bid -= 192; which = 1; src = wout; N = 512; k0 = (bid / 8) * 64; n0 = (bid % 8) * 64; }
  int tx = threadIdx.x & 63, ty = threadIdx.x >> 6;
#pragma unroll
  for (int i = 0; i < 16; ++i) {
    int row = ty + i * 4;
    tile[row][tx] = src[(k0 + row) * N + n0 + tx];
  }
  __syncthreads();
#pragma unroll
  for (int i = 0; i < 16; ++i) {
    int row = ty + i * 4;
    float w = tile[tx][row];
    if (which == 0) wqkvT[(n0 + row) * 512 + k0 + tx] = f2bf(w);
    else            whiT[(n0 + row) * 512 + k0 + tx] = f2bf(w);
  }
}

// ---------------------------------------------------------------------------
// qkv_gemm: double-buffered LDS + counted vmcnt(6) + raw barriers.
// 64x128 tile, 4 waves, BK=64. V-part epilogue transposed via LDS so vtb
// ([b,h,d,n]) gets 64B-contiguous stores instead of 2B scatter.
// ---------------------------------------------------------------------------
__global__ __launch_bounds__(256) void qkv_gemm(
    const unsigned short* __restrict__ A, const unsigned short* __restrict__ Bt,
    unsigned short* __restrict__ qb, unsigned short* __restrict__ kb,
    unsigned short* __restrict__ vtb) {
  __shared__ __attribute__((aligned(16))) unsigned short lA[2][64 * 64];   // 16 KB
  __shared__ __attribute__((aligned(16))) unsigned short lB[2][128 * 64];  // 32 KB
  const int lane = threadIdx.x & 63, wid = threadIdx.x >> 6;
  const int l15 = lane & 15, lg = lane >> 4;
  const int row0 = blockIdx.x * 64;
  const int col0 = blockIdx.y * 128;
  const int srow = lane >> 3;
  const int gslot = (lane & 7) ^ srow;
  f32x4 acc[4][2] = {};

#define QKV_STAGE(ks_, buf_)                                                               \
  {                                                                                        \
    const int k0_ = (ks_) * 64;                                                            \
    _Pragma("unroll") for (int i = 0; i < 2; ++i) {                                        \
      int c = wid * 2 + i;                                                                 \
      GLDS16(A + (row0 + c * 8 + srow) * 512 + k0_ + gslot * 8, &lA[buf_][c * 512]);       \
    }                                                                                      \
    _Pragma("unroll") for (int i = 0; i < 4; ++i) {                                        \
      int c = wid * 4 + i;                                                                 \
      GLDS16(Bt + (col0 + c * 8 + srow) * 512 + k0_ + gslot * 8, &lB[buf_][c * 512]);      \
    }                                                                                      \
  }

  QKV_STAGE(0, 0);
  int buf = 0;
  for (int ks = 0; ks < 8; ++ks) {
    if (ks < 7) {
      QKV_STAGE(ks + 1, buf ^ 1);
      asm volatile("s_waitcnt vmcnt(6)" ::: "memory");
    } else {
      asm volatile("s_waitcnt vmcnt(0)" ::: "memory");
    }
    __builtin_amdgcn_s_barrier();
    const unsigned short* La = &lA[buf][0];
    const unsigned short* Lb = &lB[buf][0];
#pragma unroll
    for (int ksub = 0; ksub < 2; ++ksub) {
      short8 af[4], bfr[2];
#pragma unroll
      for (int m = 0; m < 4; ++m) {
        int row = m * 16 + l15;
        int slot = (ksub * 4 + lg) ^ (row & 7);
        af[m] = *(const short8*)(La + row * 64 + slot * 8);
      }
#pragma unroll
      for (int n = 0; n < 2; ++n) {
        int row = wid * 32 + n * 16 + l15;
        int slot = (ksub * 4 + lg) ^ (row & 7);
        bfr[n] = *(const short8*)(Lb + row * 64 + slot * 8);
      }
#pragma unroll
      for (int m = 0; m < 4; ++m)
#pragma unroll
        for (int n = 0; n < 2; ++n)
          acc[m][n] = __builtin_amdgcn_mfma_f32_16x16x32_bf16(af[m], bfr[n], acc[m][n], 0, 0, 0);
    }
    __builtin_amdgcn_s_barrier();
    buf ^= 1;
  }

  if (col0 >= 1024) {
    // ---- V block: transpose via LDS scratch ([128][72] shorts over lB)
    unsigned short* T = &lB[0][0];
#pragma unroll
    for (int m = 0; m < 4; ++m)
#pragma unroll
      for (int n = 0; n < 2; ++n) {
        int lc = wid * 32 + n * 16 + l15;
#pragma unroll
        for (int r = 0; r < 4; ++r)
          T[lc * 72 + m * 16 + lg * 4 + r] = f2bf(acc[m][n][r]);
      }
    __syncthreads();
    int c = threadIdx.x >> 1, half = threadIdx.x & 1;
    int gcol = col0 + c;
    int hh = (gcol >> 6) & 7, d = gcol & 63;
    int b = row0 >> 11, np0 = row0 & 2047;
    unsigned short* dst = vtb + ((size_t)((b * 8 + hh) * 64 + d)) * 2048 + np0 + half * 32;
    const unsigned short* srcT = T + c * 72 + half * 32;
#pragma unroll
    for (int i = 0; i < 4; ++i)
      *(short8*)(dst + i * 8) = *(const short8*)(srcT + i * 8);
  } else {
#pragma unroll
    for (int m = 0; m < 4; ++m) {
#pragma unroll
      for (int n = 0; n < 2; ++n) {
        int col = col0 + wid * 32 + n * 16 + l15;
        int which = col >> 9, hh = (col >> 6) & 7, d = col & 63;
#pragma unroll
        for (int r = 0; r < 4; ++r) {
          int grow = row0 + m * 16 + lg * 4 + r;
          int b = grow >> 11, np = grow & 2047;
          float v = acc[m][n][r];
          if (which == 0)
            qb[((b * 8 + hh) * 2048 + np) * 64 + d] = f2bf(v * QSCALE);  // exp2-domain scale
          else
            kb[((b * 8 + hh) * 2048 + np) * 64 + d] = f2bf(v);
        }
      }
    }
  }
}

// ---------------------------------------------------------------------------
// attn_kernel v5: r4's proven 2-buffer/2-barrier pipeline, unrolled x2 so LDS
// buffer bases are compile-time; f32 jmask in LDS; exp2 softmax (fixed max);
// single bf16 output. Grid (16 bh, 32 q-blocks of 64), 4 waves.
// ---------------------------------------------------------------------------
__global__ __launch_bounds__(256) void attn_kernel(
    const unsigned short* __restrict__ qg, const unsigned short* __restrict__ kg,
    const unsigned short* __restrict__ vtg, const int* __restrict__ mnp,
    const float* __restrict__ jmflt, unsigned short* __restrict__ ab) {
  __shared__ __attribute__((aligned(16))) unsigned short Kbuf[2][64 * 64];  // 16 KB
  __shared__ __attribute__((aligned(16))) unsigned short Vbuf[2][64 * 64];  // 16 KB
  __shared__ __attribute__((aligned(16))) float jmlds[2048];                // 8 KB
  __shared__ __attribute__((aligned(16))) unsigned short Plds[4][16 * 72];  // 9 KB
  const int lane = threadIdx.x & 63, wid = threadIdx.x >> 6;
  const int l15 = lane & 15, lg = lane >> 4;
  const int srow = lane >> 3, gslot = (lane & 7) ^ srow;
  const int bh = blockIdx.x, b = bh >> 3, h = bh & 7;
  const int q0 = blockIdx.y * 64 + wid * 16;
  const unsigned short* Q = qg + bh * (2048 * 64);
  // strength-reduced staging bases (per-lane invariant part precomputed)
  const unsigned short* Kg = kg + bh * (2048 * 64) + (wid * 16 + srow) * 64 + gslot * 8;
  const unsigned short* Vg = vtg + bh * (64 * 2048) + (wid * 16 + srow) * 2048 + gslot * 8;

#define ASTAGE(jt_, B_)                                                                    \
  {                                                                                        \
    GLDS16(Kg + (jt_) * 4096, &Kbuf[B_][(wid * 16 + 0) * 64]);                             \
    GLDS16(Kg + (jt_) * 4096 + 512, &Kbuf[B_][(wid * 16 + 8) * 64]);                       \
    GLDS16(Vg + (jt_) * 64, &Vbuf[B_][(wid * 16 + 0) * 64]);                               \
    GLDS16(Vg + (jt_) * 64 + 16384, &Vbuf[B_][(wid * 16 + 8) * 64]);                       \
  }

  // prologue: jmask (2 instrs) then tile 0
#pragma unroll
  for (int i = 0; i < 2; ++i)
    GLDS16(jmflt + b * 2048 + wid * 512 + i * 256 + lane * 4, jmlds + wid * 512 + i * 256);
  ASTAGE(0, 0);

  short8 qf[2];
#pragma unroll
  for (int s = 0; s < 2; ++s)
    qf[s] = *(const short8*)(Q + (q0 + l15) * 64 + s * 32 + lg * 8);
  const float rowflt = (mnp[b * 2048 + q0 + l15] == 0) ? -100.0f : 1e30f;

  f32x4 accO[4] = {};
  float psum = 0.0f;
  unsigned short* Pl = &Plds[wid][0];
  const int sw = (l15 & 7) * 8;

#define AITER(jt_, CUR)                                                                    \
  {                                                                                        \
    if ((jt_) < 31) {                                                                      \
      ASTAGE((jt_) + 1, (CUR) ^ 1);                                                        \
      asm volatile("s_waitcnt vmcnt(4)" ::: "memory");                                     \
    } else {                                                                               \
      asm volatile("s_waitcnt vmcnt(0)" ::: "memory");                                     \
    }                                                                                      \
    __builtin_amdgcn_s_barrier();                                                          \
    const unsigned short* Kc = &Kbuf[CUR][0];                                              \
    const unsigned short* Vc = &Vbuf[CUR][0];                                              \
    const int j0 = (jt_) * 64;                                                             \
    short8 kf[4][2], vf[4][2];                                                             \
    _Pragma("unroll") for (int t = 0; t < 4; ++t) {                                        \
      const int row = t * 16 + l15;                                                        \
      _Pragma("unroll") for (int s = 0; s < 2; ++s)                                        \
          kf[t][s] = *(const short8*)(&Kc[row * 64 + ((s * 32 + lg * 8) ^ sw)]);           \
    }                                                                                      \
    _Pragma("unroll") for (int dt = 0; dt < 4; ++dt) {                                     \
      const int row = dt * 16 + l15;                                                       \
      _Pragma("unroll") for (int c = 0; c < 2; ++c)                                        \
          vf[dt][c] = *(const short8*)(&Vc[row * 64 + ((c * 32 + lg * 8) ^ sw)]);          \
    }                                                                                      \
    f32x4 sacc[4] = {};                                                                    \
    _Pragma("unroll") for (int t = 0; t < 4; ++t)                                          \
        _Pragma("unroll") for (int s = 0; s < 2; ++s)                                      \
            sacc[t] = __builtin_amdgcn_mfma_f32_16x16x32_bf16(kf[t][s], qf[s], sacc[t],    \
                                                              0, 0, 0);                    \
    _Pragma("unroll") for (int t = 0; t < 4; ++t) {                                        \
      f32x4 jm = *(const f32x4*)(&jmlds[j0 + t * 16 + lg * 4]);                            \
      float e[4];                                                                          \
      _Pragma("unroll") for (int r = 0; r < 4; ++r) {                                      \
        float sv = fminf(fminf(sacc[t][r], jm[r]), rowflt);                                \
        e[r] = exp2f(sv);                                                                  \
        psum += e[r];                                                                      \
      }                                                                                    \
      *(unsigned*)(Pl + l15 * 72 + t * 16 + lg * 4 + 0) = cvt_pk_bf16(e[0], e[1]);         \
      *(unsigned*)(Pl + l15 * 72 + t * 16 + lg * 4 + 2) = cvt_pk_bf16(e[2], e[3]);         \
    }                                                                                      \
    short8 pa[2];                                                                          \
    _Pragma("unroll") for (int c = 0; c < 2; ++c)                                          \
        pa[c] = *(const short8*)(Pl + l15 * 72 + c * 32 + lg * 8);                         \
    _Pragma("unroll") for (int dt = 0; dt < 4; ++dt)                                       \
        _Pragma("unroll") for (int c = 0; c < 2; ++c)                                      \
            accO[dt] = __builtin_amdgcn_mfma_f32_16x16x32_bf16(pa[c], vf[dt][c], accO[dt], \
                                                               0, 0, 0);                   \
    __builtin_amdgcn_s_barrier();                                                          \
  }

  for (int jt2 = 0; jt2 < 16; ++jt2) {
    AITER(jt2 * 2, 0);
    AITER(jt2 * 2 + 1, 1);
  }

  // ---- epilogue: row-sum reduce, normalize, bf16 store
  psum += __shfl_xor(psum, 16);
  psum += __shfl_xor(psum, 32);
  float lsum[4];
#pragma unroll
  for (int r = 0; r < 4; ++r) lsum[r] = 1.0f / __shfl(psum, lg * 4 + r);
#pragma unroll
  for (int dt = 0; dt < 4; ++dt) {
#pragma unroll
    for (int r = 0; r < 4; ++r) {
      float val = accO[dt][r] * lsum[r];
      int row = q0 + lg * 4 + r;
      int col = h * 64 + dt * 16 + l15;
      ab[(b * 2048 + row) * 512 + col] = f2bf(val);
    }
  }
}

// ---------------------------------------------------------------------------
// outproj_gemm v3: plain bf16 GEMM (split dropped — error budget allows).
// out[4096][512] = ab[4096][512] @ Wout + bias. 64x128 tile, 4 waves, dbuf.
// ---------------------------------------------------------------------------
__global__ __launch_bounds__(256) void outproj_gemm(
    const unsigned short* __restrict__ A, const unsigned short* __restrict__ Bt,
    const float* __restrict__ bias, float* __restrict__ out) {
  __shared__ __attribute__((aligned(16))) unsigned short lA[2][64 * 64];
  __shared__ __attribute__((aligned(16))) unsigned short lB[2][128 * 64];
  const int lane = threadIdx.x & 63, wid = threadIdx.x >> 6;
  const int l15 = lane & 15, lg = lane >> 4;
  const int row0 = blockIdx.x * 64;
  const int col0 = blockIdx.y * 128;
  const int srow = lane >> 3;
  const int gslot = (lane & 7) ^ srow;
  f32x4 acc[4][2] = {};

#define OP_STAGE(ks_, buf_)                                                                \
  {                                                                                        \
    const int k0_ = (ks_) * 64;                                                            \
    _Pragma("unroll") for (int i = 0; i < 2; ++i) {                                        \
      int c = wid * 2 + i;                                                                 \
      GLDS16(A + (row0 + c * 8 + srow) * 512 + k0_ + gslot * 8, &lA[buf_][c * 512]);       \
    }                                                                                      \
    _Pragma("unroll") for (int i = 0; i < 4; ++i) {                                        \
      int c = wid * 4 + i;                                                                 \
      GLDS16(Bt + (col0 + c * 8 + srow) * 512 + k0_ + gslot * 8, &lB[buf_][c * 512]);      \
    }                                                                                      \
  }

  OP_STAGE(0, 0);
  int buf = 0;
  for (int ks = 0; ks < 8; ++ks) {
    if (ks < 7) {
      OP_STAGE(ks + 1, buf ^ 1);
      asm volatile("s_waitcnt vmcnt(6)" ::: "memory");
    } else {
      asm volatile("s_waitcnt vmcnt(0)" ::: "memory");
    }
    __builtin_amdgcn_s_barrier();
    const unsigned short* La = &lA[buf][0];
    const unsigned short* Lb = &lB[buf][0];
#pragma unroll
    for (int ksub = 0; ksub < 2; ++ksub) {
      short8 af[4], bfr[2];
#pragma unroll
      for (int m = 0; m < 4; ++m) {
        int row = m * 16 + l15;
        int slot = (ksub * 4 + lg) ^ (row & 7);
        af[m] = *(const short8*)(La + row * 64 + slot * 8);
      }
#pragma unroll
      for (int n = 0; n < 2; ++n) {
        int row = wid * 32 + n * 16 + l15;
        int slot = (ksub * 4 + lg) ^ (row & 7);
        bfr[n] = *(const short8*)(Lb + row * 64 + slot * 8);
      }
#pragma unroll
      for (int m = 0; m < 4; ++m)
#pragma unroll
        for (int n = 0; n < 2; ++n)
          acc[m][n] = __builtin_amdgcn_mfma_f32_16x16x32_bf16(af[m], bfr[n], acc[m][n], 0, 0, 0);
    }
    __builtin_amdgcn_s_barrier();
    buf ^= 1;
  }
#pragma unroll
  for (int m = 0; m < 4; ++m) {
#pragma unroll
    for (int n = 0; n < 2; ++n) {
      int col = col0 + wid * 32 + n * 16 + l15;
      float bb = bias[col];
#pragma unroll
      for (int r = 0; r < 4; ++r) {
        int grow = row0 + m * 16 + lg * 4 + r;
        out[grow * 512 + col] = acc[m][n][r] + bb;
      }
    }
  }
}

// ---------------------------------------------------------------------------
extern "C" void kernel_launch(void* const* d_in, const int* in_sizes, int n_in,
                              void* d_out, int out_size, void* d_ws, size_t ws_size,
                              hipStream_t stream) {
  (void)in_sizes; (void)n_in; (void)out_size; (void)ws_size;
  const float* x = (const float*)d_in[0];
  const int* mnp = (const int*)d_in[1];
  const int* mbert = (const int*)d_in[2];
  const float* wqkv = (const float*)d_in[3];
  const float* wout = (const float*)d_in[4];
  const float* bout = (const float*)d_in[5];
  float* out = (float*)d_out;

  char* ws = (char*)d_ws;
  size_t off = 0;
  auto alloc = [&](size_t bytes) {
    void* p = ws + off;
    off += (bytes + 255) & ~(size_t)255;
    return p;
  };
  unsigned short* xb    = (unsigned short*)alloc(2097152 * 2);   // x bf16 [4096][512]
  unsigned short* wqkvT = (unsigned short*)alloc(786432 * 2);    // [1536][512]
  unsigned short* qb    = (unsigned short*)alloc(2097152 * 2);   // [b,h,n,d] (xQSCALE)
  unsigned short* kb    = (unsigned short*)alloc(2097152 * 2);   // [b,h,n,d]
  unsigned short* vtb   = (unsigned short*)alloc(2097152 * 2);   // [b,h,d,n]
  unsigned short* ab    = (unsigned short*)alloc(2097152 * 2);   // attn out bf16
  unsigned short* whiT  = (unsigned short*)alloc(262144 * 2);    // [512][512] n-major
  float* jmflt          = (float*)alloc(4096 * 4);

  prep_x<<<2064, 256, 0, stream>>>(x, mnp, mbert, xb, jmflt);
  transpose_w<<<256, 256, 0, stream>>>(wqkv, wout, wqkvT, whiT);
  qkv_gemm<<<dim3(64, 12), 256, 0, stream>>>(xb, wqkvT, qb, kb, vtb);
  attn_kernel<<<dim3(16, 32), 256, 0, stream>>>(qb, kb, vtb, mnp, jmflt, ab);
  outproj_gemm<<<dim3(64, 4), 256, 0, stream>>>(ab, whiT, bout, out);
}

// Round 9
// 130.793 us; speedup vs baseline: 1.1019x; 1.0209x over previous
//
#include <hip/hip_runtime.h>

typedef __attribute__((ext_vector_type(8))) short short8;
typedef __attribute__((ext_vector_type(4))) float f32x4;

#define GLDS16(gp, lp)                                                                     \
  __builtin_amdgcn_global_load_lds(                                                        \
      (const __attribute__((address_space(1))) unsigned int*)(gp),                         \
      (__attribute__((address_space(3))) unsigned int*)(lp), 16, 0, 0)

__device__ __forceinline__ unsigned short f2bf(float f) {
  unsigned u = __float_as_uint(f);
  u += 0x7FFFu + ((u >> 16) & 1u);
  return (unsigned short)(u >> 16);
}
__device__ __forceinline__ float bf2f(unsigned short h) {
  return __uint_as_float(((unsigned)h) << 16);
}
__device__ __forceinline__ unsigned cvt_pk_bf16(float a, float b) {
  unsigned r;
  asm("v_cvt_pk_bf16_f32 %0, %1, %2" : "=v"(r) : "v"(a), "v"(b));
  return r;  // lo16 = bf16(a), hi16 = bf16(b)
}

#define QSCALE 0.1803368801111244f  /* 0.125 * log2(e): QK logits land in exp2 domain */

// ---------------------------------------------------------------------------
// prep_kernel (merged): blocks 0..2063: x->bf16 + jmflt; blocks 2064..2319:
// LDS-tiled 64x64 weight transposes (coalesced both sides).
// ---------------------------------------------------------------------------
__global__ __launch_bounds__(256) void prep_kernel(
    const float* __restrict__ x, const int* __restrict__ mnp, const int* __restrict__ mbert,
    const float* __restrict__ wqkv, const float* __restrict__ wout,
    unsigned short* __restrict__ xb, float* __restrict__ jmflt,
    unsigned short* __restrict__ wqkvT, unsigned short* __restrict__ whiT) {
  __shared__ float tile[64][65];
  int bid = blockIdx.x;
  if (bid < 2064) {
    int tid = bid * 256 + threadIdx.x;
    if (tid < 524288) {
      float4 v = *(const float4*)(x + tid * 4);
      ushort4 o;
      o.x = f2bf(v.x); o.y = f2bf(v.y); o.z = f2bf(v.z); o.w = f2bf(v.w);
      *(ushort4*)(xb + tid * 4) = o;
    } else {
      int o = tid - 524288;  // 0..4095
      jmflt[o] = (mnp[o] == 0 || mbert[o] == 1) ? -100.0f : 1e30f;
    }
    return;
  }
  bid -= 2064;
  const float* src;
  int N, k0, n0, which;
  if (bid < 192) { which = 0; src = wqkv; N = 1536; k0 = (bid / 24) * 64; n0 = (bid % 24) * 64; }
  else { bid -= 192; which = 1; src = wout; N = 512; k0 = (bid / 8) * 64; n0 = (bid % 8) * 64; }
  int tx = threadIdx.x & 63, ty = threadIdx.x >> 6;
#pragma unroll
  for (int i = 0; i < 16; ++i) {
    int row = ty + i * 4;
    tile[row][tx] = src[(k0 + row) * N + n0 + tx];
  }
  __syncthreads();
#pragma unroll
  for (int i = 0; i < 16; ++i) {
    int row = ty + i * 4;
    float w = tile[tx][row];
    if (which == 0) wqkvT[(n0 + row) * 512 + k0 + tx] = f2bf(w);
    else            whiT[(n0 + row) * 512 + k0 + tx] = f2bf(w);
  }
}

// ---------------------------------------------------------------------------
// qkv_gemm: double-buffered LDS + counted vmcnt(6) + raw barriers. 64x128 tile.
// (unchanged from r6 — passed at 133.5 µs total)
// ---------------------------------------------------------------------------
__global__ __launch_bounds__(256) void qkv_gemm(
    const unsigned short* __restrict__ A, const unsigned short* __restrict__ Bt,
    unsigned short* __restrict__ qb, unsigned short* __restrict__ kb,
    unsigned short* __restrict__ vtb) {
  __shared__ __attribute__((aligned(16))) unsigned short lA[2][64 * 64];   // 16 KB
  __shared__ __attribute__((aligned(16))) unsigned short lB[2][128 * 64];  // 32 KB
  const int lane = threadIdx.x & 63, wid = threadIdx.x >> 6;
  const int l15 = lane & 15, lg = lane >> 4;
  const int row0 = blockIdx.x * 64;
  const int col0 = blockIdx.y * 128;
  const int srow = lane >> 3;
  const int gslot = (lane & 7) ^ srow;
  f32x4 acc[4][2] = {};

#define QKV_STAGE(ks_, buf_)                                                               \
  {                                                                                        \
    const int k0_ = (ks_) * 64;                                                            \
    _Pragma("unroll") for (int i = 0; i < 2; ++i) {                                        \
      int c = wid * 2 + i;                                                                 \
      GLDS16(A + (row0 + c * 8 + srow) * 512 + k0_ + gslot * 8, &lA[buf_][c * 512]);       \
    }                                                                                      \
    _Pragma("unroll") for (int i = 0; i < 4; ++i) {                                        \
      int c = wid * 4 + i;                                                                 \
      GLDS16(Bt + (col0 + c * 8 + srow) * 512 + k0_ + gslot * 8, &lB[buf_][c * 512]);      \
    }                                                                                      \
  }

  QKV_STAGE(0, 0);
  int buf = 0;
  for (int ks = 0; ks < 8; ++ks) {
    if (ks < 7) {
      QKV_STAGE(ks + 1, buf ^ 1);
      asm volatile("s_waitcnt vmcnt(6)" ::: "memory");
    } else {
      asm volatile("s_waitcnt vmcnt(0)" ::: "memory");
    }
    __builtin_amdgcn_s_barrier();
    const unsigned short* La = &lA[buf][0];
    const unsigned short* Lb = &lB[buf][0];
#pragma unroll
    for (int ksub = 0; ksub < 2; ++ksub) {
      short8 af[4], bfr[2];
#pragma unroll
      for (int m = 0; m < 4; ++m) {
        int row = m * 16 + l15;
        int slot = (ksub * 4 + lg) ^ (row & 7);
        af[m] = *(const short8*)(La + row * 64 + slot * 8);
      }
#pragma unroll
      for (int n = 0; n < 2; ++n) {
        int row = wid * 32 + n * 16 + l15;
        int slot = (ksub * 4 + lg) ^ (row & 7);
        bfr[n] = *(const short8*)(Lb + row * 64 + slot * 8);
      }
#pragma unroll
      for (int m = 0; m < 4; ++m)
#pragma unroll
        for (int n = 0; n < 2; ++n)
          acc[m][n] = __builtin_amdgcn_mfma_f32_16x16x32_bf16(af[m], bfr[n], acc[m][n], 0, 0, 0);
    }
    __builtin_amdgcn_s_barrier();
    buf ^= 1;
  }

  if (col0 >= 1024) {
    unsigned short* T = &lB[0][0];
#pragma unroll
    for (int m = 0; m < 4; ++m)
#pragma unroll
      for (int n = 0; n < 2; ++n) {
        int lc = wid * 32 + n * 16 + l15;
#pragma unroll
        for (int r = 0; r < 4; ++r)
          T[lc * 72 + m * 16 + lg * 4 + r] = f2bf(acc[m][n][r]);
      }
    __syncthreads();
    int c = threadIdx.x >> 1, half = threadIdx.x & 1;
    int gcol = col0 + c;
    int hh = (gcol >> 6) & 7, d = gcol & 63;
    int b = row0 >> 11, np0 = row0 & 2047;
    unsigned short* dst = vtb + ((size_t)((b * 8 + hh) * 64 + d)) * 2048 + np0 + half * 32;
    const unsigned short* srcT = T + c * 72 + half * 32;
#pragma unroll
    for (int i = 0; i < 4; ++i)
      *(short8*)(dst + i * 8) = *(const short8*)(srcT + i * 8);
  } else {
#pragma unroll
    for (int m = 0; m < 4; ++m) {
#pragma unroll
      for (int n = 0; n < 2; ++n) {
        int col = col0 + wid * 32 + n * 16 + l15;
        int which = col >> 9, hh = (col >> 6) & 7, d = col & 63;
#pragma unroll
        for (int r = 0; r < 4; ++r) {
          int grow = row0 + m * 16 + lg * 4 + r;
          int b = grow >> 11, np = grow & 2047;
          float v = acc[m][n][r];
          if (which == 0)
            qb[((b * 8 + hh) * 2048 + np) * 64 + d] = f2bf(v * QSCALE);
          else
            kb[((b * 8 + hh) * 2048 + np) * 64 + d] = f2bf(v);
        }
      }
    }
  }
}

// ---------------------------------------------------------------------------
// attn_kernel: EXACT r6 kernel (passed, 43.8 µs). 2-buf/2-barrier pipeline,
// unrolled x2, f32 jmask LDS, fixed-max exp2 softmax, single bf16 output.
// Grid (16 bh, 32 q-blocks of 64), 4 waves.
// ---------------------------------------------------------------------------
__global__ __launch_bounds__(256) void attn_kernel(
    const unsigned short* __restrict__ qg, const unsigned short* __restrict__ kg,
    const unsigned short* __restrict__ vtg, const int* __restrict__ mnp,
    const float* __restrict__ jmflt, unsigned short* __restrict__ ab) {
  __shared__ __attribute__((aligned(16))) unsigned short Kbuf[2][64 * 64];  // 16 KB
  __shared__ __attribute__((aligned(16))) unsigned short Vbuf[2][64 * 64];  // 16 KB
  __shared__ __attribute__((aligned(16))) float jmlds[2048];                // 8 KB
  __shared__ __attribute__((aligned(16))) unsigned short Plds[4][16 * 72];  // 9 KB
  const int lane = threadIdx.x & 63, wid = threadIdx.x >> 6;
  const int l15 = lane & 15, lg = lane >> 4;
  const int srow = lane >> 3, gslot = (lane & 7) ^ srow;
  const int bh = blockIdx.x, b = bh >> 3, h = bh & 7;
  const int q0 = blockIdx.y * 64 + wid * 16;
  const unsigned short* Q = qg + bh * (2048 * 64);
  const unsigned short* Kg = kg + bh * (2048 * 64) + (wid * 16 + srow) * 64 + gslot * 8;
  const unsigned short* Vg = vtg + bh * (64 * 2048) + (wid * 16 + srow) * 2048 + gslot * 8;

#define ASTAGE(jt_, B_)                                                                    \
  {                                                                                        \
    GLDS16(Kg + (jt_) * 4096, &Kbuf[B_][(wid * 16 + 0) * 64]);                             \
    GLDS16(Kg + (jt_) * 4096 + 512, &Kbuf[B_][(wid * 16 + 8) * 64]);                       \
    GLDS16(Vg + (jt_) * 64, &Vbuf[B_][(wid * 16 + 0) * 64]);                               \
    GLDS16(Vg + (jt_) * 64 + 16384, &Vbuf[B_][(wid * 16 + 8) * 64]);                       \
  }

#pragma unroll
  for (int i = 0; i < 2; ++i)
    GLDS16(jmflt + b * 2048 + wid * 512 + i * 256 + lane * 4, jmlds + wid * 512 + i * 256);
  ASTAGE(0, 0);

  short8 qf[2];
#pragma unroll
  for (int s = 0; s < 2; ++s)
    qf[s] = *(const short8*)(Q + (q0 + l15) * 64 + s * 32 + lg * 8);
  const float rowflt = (mnp[b * 2048 + q0 + l15] == 0) ? -100.0f : 1e30f;

  f32x4 accO[4] = {};
  float psum = 0.0f;
  unsigned short* Pl = &Plds[wid][0];
  const int sw = (l15 & 7) * 8;

#define AITER(jt_, CUR)                                                                    \
  {                                                                                        \
    if ((jt_) < 31) {                                                                      \
      ASTAGE((jt_) + 1, (CUR) ^ 1);                                                        \
      asm volatile("s_waitcnt vmcnt(4)" ::: "memory");                                     \
    } else {                                                                               \
      asm volatile("s_waitcnt vmcnt(0)" ::: "memory");                                     \
    }                                                                                      \
    __builtin_amdgcn_s_barrier();                                                          \
    const unsigned short* Kc = &Kbuf[CUR][0];                                              \
    const unsigned short* Vc = &Vbuf[CUR][0];                                              \
    const int j0 = (jt_) * 64;                                                             \
    short8 kf[4][2], vf[4][2];                                                             \
    _Pragma("unroll") for (int t = 0; t < 4; ++t) {                                        \
      const int row = t * 16 + l15;                                                        \
      _Pragma("unroll") for (int s = 0; s < 2; ++s)                                        \
          kf[t][s] = *(const short8*)(&Kc[row * 64 + ((s * 32 + lg * 8) ^ sw)]);           \
    }                                                                                      \
    _Pragma("unroll") for (int dt = 0; dt < 4; ++dt) {                                     \
      const int row = dt * 16 + l15;                                                       \
      _Pragma("unroll") for (int c = 0; c < 2; ++c)                                        \
          vf[dt][c] = *(const short8*)(&Vc[row * 64 + ((c * 32 + lg * 8) ^ sw)]);          \
    }                                                                                      \
    f32x4 sacc[4] = {};                                                                    \
    _Pragma("unroll") for (int t = 0; t < 4; ++t)                                          \
        _Pragma("unroll") for (int s = 0; s < 2; ++s)                                      \
            sacc[t] = __builtin_amdgcn_mfma_f32_16x16x32_bf16(kf[t][s], qf[s], sacc[t],    \
                                                              0, 0, 0);                    \
    _Pragma("unroll") for (int t = 0; t < 4; ++t) {                                        \
      f32x4 jm = *(const f32x4*)(&jmlds[j0 + t * 16 + lg * 4]);                            \
      float e[4];                                                                          \
      _Pragma("unroll") for (int r = 0; r < 4; ++r) {                                      \
        float sv = fminf(fminf(sacc[t][r], jm[r]), rowflt);                                \
        e[r] = exp2f(sv);                                                                  \
        psum += e[r];                                                                      \
      }                                                                                    \
      *(unsigned*)(Pl + l15 * 72 + t * 16 + lg * 4 + 0) = cvt_pk_bf16(e[0], e[1]);         \
      *(unsigned*)(Pl + l15 * 72 + t * 16 + lg * 4 + 2) = cvt_pk_bf16(e[2], e[3]);         \
    }                                                                                      \
    short8 pa[2];                                                                          \
    _Pragma("unroll") for (int c = 0; c < 2; ++c)                                          \
        pa[c] = *(const short8*)(Pl + l15 * 72 + c * 32 + lg * 8);                         \
    _Pragma("unroll") for (int dt = 0; dt < 4; ++dt)                                       \
        _Pragma("unroll") for (int c = 0; c < 2; ++c)                                      \
            accO[dt] = __builtin_amdgcn_mfma_f32_16x16x32_bf16(pa[c], vf[dt][c], accO[dt], \
                                                               0, 0, 0);                   \
    __builtin_amdgcn_s_barrier();                                                          \
  }

  for (int jt2 = 0; jt2 < 16; ++jt2) {
    AITER(jt2 * 2, 0);
    AITER(jt2 * 2 + 1, 1);
  }

  psum += __shfl_xor(psum, 16);
  psum += __shfl_xor(psum, 32);
  float lsum[4];
#pragma unroll
  for (int r = 0; r < 4; ++r) lsum[r] = 1.0f / __shfl(psum, lg * 4 + r);
#pragma unroll
  for (int dt = 0; dt < 4; ++dt) {
#pragma unroll
    for (int r = 0; r < 4; ++r) {
      float val = accO[dt][r] * lsum[r];
      int row = q0 + lg * 4 + r;
      int col = h * 64 + dt * 16 + l15;
      ab[(b * 2048 + row) * 512 + col] = f2bf(val);
    }
  }
}

// ---------------------------------------------------------------------------
// outproj_gemm: plain bf16 GEMM, 32x128 tile (r5-proven structure), grid
// (128,4)=512 blocks for 2+ blocks/CU. dbuf + vmcnt(5).
// ---------------------------------------------------------------------------
__global__ __launch_bounds__(256) void outproj_gemm(
    const unsigned short* __restrict__ A, const unsigned short* __restrict__ Bt,
    const float* __restrict__ bias, float* __restrict__ out) {
  __shared__ __attribute__((aligned(16))) unsigned short lA[2][32 * 64];   // 8 KB
  __shared__ __attribute__((aligned(16))) unsigned short lB[2][128 * 64];  // 32 KB
  const int lane = threadIdx.x & 63, wid = threadIdx.x >> 6;
  const int l15 = lane & 15, lg = lane >> 4;
  const int row0 = blockIdx.x * 32;
  const int col0 = blockIdx.y * 128;
  const int srow = lane >> 3;
  const int gslot = (lane & 7) ^ srow;
  f32x4 acc[2][2] = {};

#define OP_STAGE(ks_, buf_)                                                                \
  {                                                                                        \
    const int k0_ = (ks_) * 64;                                                            \
    GLDS16(A + (row0 + wid * 8 + srow) * 512 + k0_ + gslot * 8, &lA[buf_][wid * 512]);     \
    _Pragma("unroll") for (int i = 0; i < 4; ++i) {                                        \
      int c = wid * 4 + i;                                                                 \
      GLDS16(Bt + (col0 + c * 8 + srow) * 512 + k0_ + gslot * 8, &lB[buf_][c * 512]);      \
    }                                                                                      \
  }

  OP_STAGE(0, 0);
  int buf = 0;
  for (int ks = 0; ks < 8; ++ks) {
    if (ks < 7) {
      OP_STAGE(ks + 1, buf ^ 1);
      asm volatile("s_waitcnt vmcnt(5)" ::: "memory");
    } else {
      asm volatile("s_waitcnt vmcnt(0)" ::: "memory");
    }
    __builtin_amdgcn_s_barrier();
    const unsigned short* La = &lA[buf][0];
    const unsigned short* Lb = &lB[buf][0];
#pragma unroll
    for (int ksub = 0; ksub < 2; ++ksub) {
      short8 af[2], bfr[2];
#pragma unroll
      for (int m = 0; m < 2; ++m) {
        int row = m * 16 + l15;
        int slot = (ksub * 4 + lg) ^ (row & 7);
        af[m] = *(const short8*)(La + row * 64 + slot * 8);
      }
#pragma unroll
      for (int n = 0; n < 2; ++n) {
        int row = wid * 32 + n * 16 + l15;
        int slot = (ksub * 4 + lg) ^ (row & 7);
        bfr[n] = *(const short8*)(Lb + row * 64 + slot * 8);
      }
#pragma unroll
      for (int m = 0; m < 2; ++m)
#pragma unroll
        for (int n = 0; n < 2; ++n)
          acc[m][n] = __builtin_amdgcn_mfma_f32_16x16x32_bf16(af[m], bfr[n], acc[m][n], 0, 0, 0);
    }
    __builtin_amdgcn_s_barrier();
    buf ^= 1;
  }
#pragma unroll
  for (int m = 0; m < 2; ++m) {
#pragma unroll
    for (int n = 0; n < 2; ++n) {
      int col = col0 + wid * 32 + n * 16 + l15;
      float bb = bias[col];
#pragma unroll
      for (int r = 0; r < 4; ++r) {
        int grow = row0 + m * 16 + lg * 4 + r;
        out[grow * 512 + col] = acc[m][n][r] + bb;
      }
    }
  }
}

// ---------------------------------------------------------------------------
extern "C" void kernel_launch(void* const* d_in, const int* in_sizes, int n_in,
                              void* d_out, int out_size, void* d_ws, size_t ws_size,
                              hipStream_t stream) {
  (void)in_sizes; (void)n_in; (void)out_size; (void)ws_size;
  const float* x = (const float*)d_in[0];
  const int* mnp = (const int*)d_in[1];
  const int* mbert = (const int*)d_in[2];
  const float* wqkv = (const float*)d_in[3];
  const float* wout = (const float*)d_in[4];
  const float* bout = (const float*)d_in[5];
  float* out = (float*)d_out;

  char* ws = (char*)d_ws;
  size_t off = 0;
  auto alloc = [&](size_t bytes) {
    void* p = ws + off;
    off += (bytes + 255) & ~(size_t)255;
    return p;
  };
  unsigned short* xb    = (unsigned short*)alloc(2097152 * 2);   // x bf16 [4096][512]
  unsigned short* wqkvT = (unsigned short*)alloc(786432 * 2);    // [1536][512]
  unsigned short* qb    = (unsigned short*)alloc(2097152 * 2);   // [b,h,n,d] (xQSCALE)
  unsigned short* kb    = (unsigned short*)alloc(2097152 * 2);   // [b,h,n,d]
  unsigned short* vtb   = (unsigned short*)alloc(2097152 * 2);   // [b,h,d,n]
  unsigned short* ab    = (unsigned short*)alloc(2097152 * 2);   // attn out bf16
  unsigned short* whiT  = (unsigned short*)alloc(262144 * 2);    // [512][512] n-major
  float* jmflt          = (float*)alloc(4096 * 4);

  prep_kernel<<<2320, 256, 0, stream>>>(x, mnp, mbert, wqkv, wout, xb, jmflt, wqkvT, whiT);
  qkv_gemm<<<dim3(64, 12), 256, 0, stream>>>(xb, wqkvT, qb, kb, vtb);
  attn_kernel<<<dim3(16, 32), 256, 0, stream>>>(qb, kb, vtb, mnp, jmflt, ab);
  outproj_gemm<<<dim3(128, 4), 256, 0, stream>>>(ab, whiT, bout, out);
}